// Round 1
// baseline (660.497 us; speedup 1.0000x reference)
//
#include <hip/hip_runtime.h>

// LSTM: B=2048, T=512, D=1, H=50, OUT=3, fp32.
//
// Round-2 restructure. Round-1 counters showed VGPR_Count=112 with ~610
// VALU instr/step (need ~280): the 200-weight/lane working set overflowed
// arch VGPRs into AGPRs -> accvgpr shuttling dominated.
//
// New mapping: block = 256 threads = 4 waves = ONE batch element at a time
// (2 sequential batch elements per block; grid 1024 -> all blocks resident
// at 4 waves/SIMD). Wave g owns gate g (i,f,g,o); lane j owns unit j.
// Per lane: 50 recurrent weights (one W_hh row) -> no register cliff.
// h is broadcast via LDS (13 uniform-address reads/step, conflict-free)
// instead of 50 v_readlane. Gate activations exchanged through a
// double-buffered act[] LDS array with ONE __syncthreads per step; every
// wave redundantly computes the c/h update (symmetric, no serial phase)
// and keeps its own private h slice in LDS (own-wave RAW only).

#define BB   2048
#define TT   512
#define HH   50
#define BPB  2                 // batch elements per block, sequential
#define GRID (BB / BPB)        // 1024 blocks

__device__ __forceinline__ float fast_sigmoid(float x) {
    float e = __builtin_amdgcn_exp2f(-1.4426950408889634f * x);
    return __builtin_amdgcn_rcpf(1.0f + e);
}

__device__ __forceinline__ float fast_tanh(float x) {
    float e = __builtin_amdgcn_exp2f(-2.8853900817779268f * x);  // e^{-2x}
    return __builtin_amdgcn_rcpf(1.0f + e) * 2.0f - 1.0f;
}

// Apply macro M to k = 0..49
#define REPK(M) \
  M(0)  M(1)  M(2)  M(3)  M(4)  M(5)  M(6)  M(7)  M(8)  M(9)  \
  M(10) M(11) M(12) M(13) M(14) M(15) M(16) M(17) M(18) M(19) \
  M(20) M(21) M(22) M(23) M(24) M(25) M(26) M(27) M(28) M(29) \
  M(30) M(31) M(32) M(33) M(34) M(35) M(36) M(37) M(38) M(39) \
  M(40) M(41) M(42) M(43) M(44) M(45) M(46) M(47) M(48) M(49)

__global__ __launch_bounds__(256)
__attribute__((amdgpu_waves_per_eu(4)))
void lstm_gate_kernel(const float* __restrict__ x,
                      const float* __restrict__ W_ih,
                      const float* __restrict__ W_hh,
                      const float* __restrict__ b_ih,
                      const float* __restrict__ b_hh,
                      const float* __restrict__ fc_w,
                      const float* __restrict__ fc_b,
                      float* __restrict__ out) {
    __shared__ float xs[BPB * TT];        // 4 KB: x rows for both batches
    __shared__ float hbuf[4][64];         // 1 KB: per-wave private h copy
    __shared__ float act[2][4][64];       // 2 KB: double-buffered gate acts

    const int tid  = threadIdx.x;
    // g in an SGPR: scalar branches + cheap LDS addressing
    const int g    = __builtin_amdgcn_readfirstlane((int)threadIdx.x) >> 6;
    const int lane = tid & 63;
    const int j    = (lane < HH) ? lane : (HH - 1);   // clamp idle lanes
    const bool active = (lane < HH);
    const int row  = g * HH + j;                       // W_hh row for this lane

    // Stage this block's BPB x-rows into LDS (coalesced)
    const int b0 = blockIdx.x * BPB;
    #pragma unroll
    for (int i = 0; i < (BPB * TT) / 256; ++i) {
        int idx = i * 256 + tid;
        xs[idx] = x[b0 * TT + idx];
    }
    __syncthreads();

    // 50 named weight scalars: one W_hh row per lane. k-consecutive ->
    // compiler merges into wide loads. 50 regs + working set << 128.
#define WDECL(k) const float w_##k = W_hh[row * HH + (k)];
    REPK(WDECL)
#undef WDECL

    const float wi = W_ih[row];
    const float bs = b_ih[row] + b_hh[row];

    for (int bb = 0; bb < BPB; ++bb) {
        // per-batch init: own-wave h slice (no barrier needed: only this
        // wave reads its slice, in-order LDS within a wave)
        if (active) hbuf[g][j] = 0.0f;
        float c = 0.0f, h = 0.0f;
        const float* xrow = xs + bb * TT;
        const float* hc   = hbuf[g];      // uniform addr -> broadcast reads

        #pragma unroll 1
        for (int t = 0; t < TT; ++t) {
            const int tb = t & 1;
            const float xc = xrow[t];                  // uniform LDS read
            float a0 = fmaf(xc, wi, bs);
            float a1 = 0.0f;
            // 50 FMAs against broadcast h chunks (12x float4 + 1x float2)
#define KCH(q, ka, kb, kc, kd) { \
            const float4 hv = *(const float4*)(hc + 4 * (q)); \
            a0 = fmaf(hv.x, w_##ka, a0); \
            a1 = fmaf(hv.y, w_##kb, a1); \
            a0 = fmaf(hv.z, w_##kc, a0); \
            a1 = fmaf(hv.w, w_##kd, a1); }
            KCH(0,  0,  1,  2,  3)
            KCH(1,  4,  5,  6,  7)
            KCH(2,  8,  9, 10, 11)
            KCH(3, 12, 13, 14, 15)
            KCH(4, 16, 17, 18, 19)
            KCH(5, 20, 21, 22, 23)
            KCH(6, 24, 25, 26, 27)
            KCH(7, 28, 29, 30, 31)
            KCH(8, 32, 33, 34, 35)
            KCH(9, 36, 37, 38, 39)
            KCH(10, 40, 41, 42, 43)
            KCH(11, 44, 45, 46, 47)
#undef KCH
            {
                const float2 hv = *(const float2*)(hc + 48);
                a0 = fmaf(hv.x, w_48, a0);
                a1 = fmaf(hv.y, w_49, a1);
            }
            const float a = a0 + a1;

            // own gate activation (wave-uniform scalar branch on g)
            const float v = (g == 2) ? fast_tanh(a) : fast_sigmoid(a);
            if (active) act[tb][g][j] = v;

            __syncthreads();   // the ONLY barrier per step

            // symmetric c/h update in every wave (each keeps its own c)
            const float iv = act[tb][0][j];
            const float fv = act[tb][1][j];
            const float gv = act[tb][2][j];
            const float ov = act[tb][3][j];
            c = fmaf(fv, c, iv * gv);
            h = ov * fast_tanh(c);
            if (active) hbuf[g][j] = h;   // own slice; next step reads it
        }

        // Epilogue (wave 0 has a full h copy): out[b][o] = h . fc_w[o] + b
        if (g == 0) {
            const float hv = active ? h : 0.0f;
            float r0 = hv * fc_w[0 * HH + j];
            float r1 = hv * fc_w[1 * HH + j];
            float r2 = hv * fc_w[2 * HH + j];
            #pragma unroll
            for (int off = 32; off > 0; off >>= 1) {
                r0 += __shfl_down(r0, off, 64);
                r1 += __shfl_down(r1, off, 64);
                r2 += __shfl_down(r2, off, 64);
            }
            if (lane == 0) {
                const int b = b0 + bb;
                out[b * 3 + 0] = r0 + fc_b[0];
                out[b * 3 + 1] = r1 + fc_b[1];
                out[b * 3 + 2] = r2 + fc_b[2];
            }
        }
        __syncthreads();   // cheap (2 per kernel): isolate batch iterations
    }
}

extern "C" void kernel_launch(void* const* d_in, const int* in_sizes, int n_in,
                              void* d_out, int out_size, void* d_ws, size_t ws_size,
                              hipStream_t stream) {
    const float* x    = (const float*)d_in[0];
    const float* W_ih = (const float*)d_in[1];
    const float* W_hh = (const float*)d_in[2];
    const float* b_ih = (const float*)d_in[3];
    const float* b_hh = (const float*)d_in[4];
    const float* fc_w = (const float*)d_in[5];
    const float* fc_b = (const float*)d_in[6];
    float* out = (float*)d_out;

    dim3 grid(GRID);    // 1024 blocks; 4 waves each -> all co-resident
    dim3 block(256);
    lstm_gate_kernel<<<grid, block, 0, stream>>>(x, W_ih, W_hh, b_ih, b_hh,
                                                 fc_w, fc_b, out);
}

// Round 2
// 593.008 us; speedup vs baseline: 1.1138x; 1.1138x over previous
//
#include <hip/hip_runtime.h>

// LSTM: B=2048, T=512, D=1, H=50, OUT=3, fp32.
//
// Round-3. History:
//  R1 (582us): 1 wave/batch, 200 weights/lane named-scalars, readlane
//     broadcast. VGPR=112 -> at waves_per_eu(2,2) the UNIFIED budget is
//     256/wave; ~240 live regs forced a 112-arch + ~144-acc split and
//     per-use accvgpr shuttles (~610 instr/step vs ~280 algorithmic).
//  R2 (660us): gate-split across 4 waves + LDS exchange. VGPR=40 (fixed)
//     but redundant 4-way update + per-step barrier = 320 VALU-cyc/wave-step
//     -> net regression.
//
// R3: keep R1's all-register weights, but at 1 wave/SIMD the unified
// budget is 512 -> all 200 weights live in ARCH VGPRs, no shuttles.
// Lost TLP is replaced by ILP: each wave runs TWO independent batch
// chains (shared weights, 8 interleaved gate accumulators -> dependent
// FMA distance 8). 1024 single-wave blocks, zero barriers.

#define BB   2048
#define TT   512
#define HH   50

__device__ __forceinline__ float readlane_f(float v, int lane) {
    union { float f; int i; } u;
    u.f = v;
    u.i = __builtin_amdgcn_readlane(u.i, lane);
    return u.f;
}

__device__ __forceinline__ float fast_sigmoid(float x) {
    float e = __builtin_amdgcn_exp2f(-1.4426950408889634f * x);
    return __builtin_amdgcn_rcpf(1.0f + e);
}

__device__ __forceinline__ float fast_tanh(float x) {
    float e = __builtin_amdgcn_exp2f(-2.8853900817779268f * x);  // e^{-2x}
    return __builtin_amdgcn_rcpf(1.0f + e) * 2.0f - 1.0f;
}

// Apply macro M to k = 0..49
#define REPK(M) \
  M(0)  M(1)  M(2)  M(3)  M(4)  M(5)  M(6)  M(7)  M(8)  M(9)  \
  M(10) M(11) M(12) M(13) M(14) M(15) M(16) M(17) M(18) M(19) \
  M(20) M(21) M(22) M(23) M(24) M(25) M(26) M(27) M(28) M(29) \
  M(30) M(31) M(32) M(33) M(34) M(35) M(36) M(37) M(38) M(39) \
  M(40) M(41) M(42) M(43) M(44) M(45) M(46) M(47) M(48) M(49)

__global__ __launch_bounds__(64)
__attribute__((amdgpu_waves_per_eu(1, 1)))
void lstm_dual_kernel(const float* __restrict__ x,
                      const float* __restrict__ W_ih,
                      const float* __restrict__ W_hh,
                      const float* __restrict__ b_ih,
                      const float* __restrict__ b_hh,
                      const float* __restrict__ fc_w,
                      const float* __restrict__ fc_b,
                      float* __restrict__ out) {
    __shared__ float xs[2 * TT];   // this wave's two x rows (4 KB)

    const int lane = threadIdx.x & 63;
    const int gw   = blockIdx.x;          // 0..1023
    const int bA   = gw * 2;              // two consecutive batch rows

    // Stage both x rows (2048 contiguous floats), coalesced 256B/iter.
    // Single-wave block: no barrier needed (in-order LDS within wave).
    #pragma unroll
    for (int i = 0; i < (2 * TT) / 64; ++i) {
        int idx = i * 64 + lane;
        xs[idx] = x[bA * TT + idx];
    }

    const int j = (lane < HH) ? lane : (HH - 1);   // clamp idle lanes

    // 200 named weight scalars: w{g}_{k} = W_hh[(g*H + j)*H + k].
    // Unified reg budget at 1 wave/SIMD = 512 -> all stay in arch VGPRs.
#define WDECL(k) \
    const float w0_##k = W_hh[(0 * HH + j) * HH + (k)]; \
    const float w1_##k = W_hh[(1 * HH + j) * HH + (k)]; \
    const float w2_##k = W_hh[(2 * HH + j) * HH + (k)]; \
    const float w3_##k = W_hh[(3 * HH + j) * HH + (k)];
    REPK(WDECL)
#undef WDECL

    const float wi0 = W_ih[0 * HH + j];
    const float wi1 = W_ih[1 * HH + j];
    const float wi2 = W_ih[2 * HH + j];
    const float wi3 = W_ih[3 * HH + j];
    const float bs0 = b_ih[0 * HH + j] + b_hh[0 * HH + j];
    const float bs1 = b_ih[1 * HH + j] + b_hh[1 * HH + j];
    const float bs2 = b_ih[2 * HH + j] + b_hh[2 * HH + j];
    const float bs3 = b_ih[3 * HH + j] + b_hh[3 * HH + j];

    float hA = 0.0f, cA = 0.0f, hB = 0.0f, cB = 0.0f;
    const float* xrA = xs;
    const float* xrB = xs + TT;

    float xcA = xrA[0];
    float xcB = xrB[0];
    #pragma unroll 1
    for (int t = 0; t < TT; ++t) {
        const int tn = (t + 1) & (TT - 1);
        const float xnA = xrA[tn];         // prefetch next step's x
        const float xnB = xrB[tn];
        float aiA = fmaf(xcA, wi0, bs0);
        float afA = fmaf(xcA, wi1, bs1);
        float agA = fmaf(xcA, wi2, bs2);
        float aoA = fmaf(xcA, wi3, bs3);
        float aiB = fmaf(xcB, wi0, bs0);
        float afB = fmaf(xcB, wi1, bs1);
        float agB = fmaf(xcB, wi2, bs2);
        float aoB = fmaf(xcB, wi3, bs3);
        // 100 readlanes + 400 FMAs; 8 independent accumulator chains.
#define KSTEP(k) { \
        const float hkA = readlane_f(hA, k); \
        const float hkB = readlane_f(hB, k); \
        aiA = fmaf(hkA, w0_##k, aiA); \
        afA = fmaf(hkA, w1_##k, afA); \
        agA = fmaf(hkA, w2_##k, agA); \
        aoA = fmaf(hkA, w3_##k, aoA); \
        aiB = fmaf(hkB, w0_##k, aiB); \
        afB = fmaf(hkB, w1_##k, afB); \
        agB = fmaf(hkB, w2_##k, agB); \
        aoB = fmaf(hkB, w3_##k, aoB); }
        REPK(KSTEP)
#undef KSTEP
        const float igA = fast_sigmoid(aiA);
        const float fgA = fast_sigmoid(afA);
        const float ggA = fast_tanh(agA);
        const float ogA = fast_sigmoid(aoA);
        const float igB = fast_sigmoid(aiB);
        const float fgB = fast_sigmoid(afB);
        const float ggB = fast_tanh(agB);
        const float ogB = fast_sigmoid(aoB);
        cA = fmaf(fgA, cA, igA * ggA);
        cB = fmaf(fgB, cB, igB * ggB);
        hA = ogA * fast_tanh(cA);
        hB = ogB * fast_tanh(cB);
        xcA = xnA;
        xcB = xnB;
    }

    // Epilogue: out[b][o] = sum_j h_j * fc_w[o][j] + fc_b[o], both chains.
    const float fw0 = fc_w[0 * HH + j];
    const float fw1 = fc_w[1 * HH + j];
    const float fw2 = fc_w[2 * HH + j];
    const float hvA = (lane < HH) ? hA : 0.0f;
    const float hvB = (lane < HH) ? hB : 0.0f;
    float r0A = hvA * fw0, r1A = hvA * fw1, r2A = hvA * fw2;
    float r0B = hvB * fw0, r1B = hvB * fw1, r2B = hvB * fw2;
    #pragma unroll
    for (int off = 32; off > 0; off >>= 1) {
        r0A += __shfl_down(r0A, off, 64);
        r1A += __shfl_down(r1A, off, 64);
        r2A += __shfl_down(r2A, off, 64);
        r0B += __shfl_down(r0B, off, 64);
        r1B += __shfl_down(r1B, off, 64);
        r2B += __shfl_down(r2B, off, 64);
    }
    if (lane == 0) {
        out[bA * 3 + 0] = r0A + fc_b[0];
        out[bA * 3 + 1] = r1A + fc_b[1];
        out[bA * 3 + 2] = r2A + fc_b[2];
        out[(bA + 1) * 3 + 0] = r0B + fc_b[0];
        out[(bA + 1) * 3 + 1] = r1B + fc_b[1];
        out[(bA + 1) * 3 + 2] = r2B + fc_b[2];
    }
}

extern "C" void kernel_launch(void* const* d_in, const int* in_sizes, int n_in,
                              void* d_out, int out_size, void* d_ws, size_t ws_size,
                              hipStream_t stream) {
    const float* x    = (const float*)d_in[0];
    const float* W_ih = (const float*)d_in[1];
    const float* W_hh = (const float*)d_in[2];
    const float* b_ih = (const float*)d_in[3];
    const float* b_hh = (const float*)d_in[4];
    const float* fc_w = (const float*)d_in[5];
    const float* fc_b = (const float*)d_in[6];
    float* out = (float*)d_out;

    dim3 grid(BB / 2);    // 1024 single-wave blocks: 1 wave/SIMD, 2 chains each
    dim3 block(64);
    lstm_dual_kernel<<<grid, block, 0, stream>>>(x, W_ih, W_hh, b_ih, b_hh,
                                                 fc_w, fc_b, out);
}

// Round 3
// 539.168 us; speedup vs baseline: 1.2250x; 1.0999x over previous
//
#include <hip/hip_runtime.h>

// LSTM: B=2048, T=512, D=1, H=50, OUT=3, fp32.
//
// R4. History:
//  R1 582us: 1 wave/batch, 200 reg-weights, readlane. VGPR=112 -> RA evicted
//     weights to AGPRs (112+144=256 = unified budget), accvgpr shuttles,
//     2.2x instr inflation.
//  R2 660us: gate-split across 4 waves, VGPR=40 (no cliff) but 4x redundant
//     update + per-step barrier.
//  R3 575us: dual-chain, waves_per_eu(1,1). VGPR=132, SAME 2.2x inflation:
//     at ~230 live the greedy RA mass-evicts the equal-spill-weight
//     loop-invariant weights to AGPRs regardless of the 512 unified budget.
//
// R4: keep live pressure ~150 (<< 256 arch cap) so the cliff cannot trigger:
//  - 2 waves per batch-pair: wave 0 owns gates (i,f), wave 1 owns (g,o)
//    -> 100 weights/lane.
//  - h broadcast via 13 uniform-address ds_read_b128 (wave broadcast,
//    conflict-free) instead of 50 v_readlane.
//  - 2 batch chains per wave (ILP: 4 accumulator chains, dep distance 8)
//    amortize the barrier and h-reads.
//  - activations exchanged via double-buffered float2 LDS slots; both waves
//    redundantly update c/h (cheap) -> ONE __syncthreads per step.
//  Blocks: 128 thr (2 waves) x 1024 = 2048 waves = 2/SIMD (budget 256).

#define BB   2048
#define TT   512
#define HH   50

__device__ __forceinline__ float fast_sigmoid(float x) {
    float e = __builtin_amdgcn_exp2f(-1.4426950408889634f * x);
    return __builtin_amdgcn_rcpf(1.0f + e);
}

__device__ __forceinline__ float fast_tanh(float x) {
    float e = __builtin_amdgcn_exp2f(-2.8853900817779268f * x);  // e^{-2x}
    return __builtin_amdgcn_rcpf(1.0f + e) * 2.0f - 1.0f;
}

// Apply macro M to k = 0..49
#define REPK(M) \
  M(0)  M(1)  M(2)  M(3)  M(4)  M(5)  M(6)  M(7)  M(8)  M(9)  \
  M(10) M(11) M(12) M(13) M(14) M(15) M(16) M(17) M(18) M(19) \
  M(20) M(21) M(22) M(23) M(24) M(25) M(26) M(27) M(28) M(29) \
  M(30) M(31) M(32) M(33) M(34) M(35) M(36) M(37) M(38) M(39) \
  M(40) M(41) M(42) M(43) M(44) M(45) M(46) M(47) M(48) M(49)

__global__ __launch_bounds__(128)
__attribute__((amdgpu_waves_per_eu(2, 2)))
void lstm_pair_kernel(const float* __restrict__ x,
                      const float* __restrict__ W_ih,
                      const float* __restrict__ W_hh,
                      const float* __restrict__ b_ih,
                      const float* __restrict__ b_hh,
                      const float* __restrict__ fc_w,
                      const float* __restrict__ fc_b,
                      float* __restrict__ out) {
    __shared__ float xs[2 * TT];                       // 4 KB: both x rows
    __shared__ __align__(16) float hbuf[2][2][52];     // [wave][chain][unit]
    __shared__ float2 acts[2][2][2][64];               // [t&1][chain][wave][unit]

    const int tid  = threadIdx.x;
    const int w    = __builtin_amdgcn_readfirstlane((int)(threadIdx.x >> 6));
    const int lane = tid & 63;
    const int j    = (lane < HH) ? lane : (HH - 1);    // clamp idle lanes
    const int bA   = blockIdx.x * 2;

    // Stage both x rows (coalesced)
    #pragma unroll
    for (int i = 0; i < (2 * TT) / 128; ++i) {
        int idx = i * 128 + tid;
        xs[idx] = x[bA * TT + idx];
    }
    // Zero own wave's h buffers (own-wave read only)
    if (lane < 52) {
        hbuf[w][0][lane] = 0.0f;
        hbuf[w][1][lane] = 0.0f;
    }
    __syncthreads();

    // 100 named weight scalars: rows for gates g0=2w, g1=2w+1.
    const int g0 = 2 * w, g1 = 2 * w + 1;
#define WDECL(k) \
    const float wa_##k = W_hh[(g0 * HH + j) * HH + (k)]; \
    const float wb_##k = W_hh[(g1 * HH + j) * HH + (k)];
    REPK(WDECL)
#undef WDECL

    const float wi0 = W_ih[g0 * HH + j];
    const float wi1 = W_ih[g1 * HH + j];
    const float bs0 = b_ih[g0 * HH + j] + b_hh[g0 * HH + j];
    const float bs1 = b_ih[g1 * HH + j] + b_hh[g1 * HH + j];

    float cA = 0.0f, cB = 0.0f, hAr = 0.0f, hBr = 0.0f;
    const float* hpA = hbuf[w][0];     // uniform-addr reads -> broadcast
    const float* hpB = hbuf[w][1];

    #pragma unroll 1
    for (int t = 0; t < TT; ++t) {
        const float xA = xs[t];            // uniform LDS reads
        const float xB = xs[TT + t];
        float a0A = fmaf(xA, wi0, bs0);
        float a1A = fmaf(xA, wi1, bs1);
        float a0B = fmaf(xB, wi0, bs0);
        float a1B = fmaf(xB, wi1, bs1);
        // 200 FMAs against broadcast h chunks; 4 independent acc chains.
#define KCH(q, k0, k1, k2, k3) { \
        const float4 vA = *(const float4*)(hpA + 4 * (q)); \
        const float4 vB = *(const float4*)(hpB + 4 * (q)); \
        a0A = fmaf(vA.x, wa_##k0, a0A); a1A = fmaf(vA.x, wb_##k0, a1A); \
        a0B = fmaf(vB.x, wa_##k0, a0B); a1B = fmaf(vB.x, wb_##k0, a1B); \
        a0A = fmaf(vA.y, wa_##k1, a0A); a1A = fmaf(vA.y, wb_##k1, a1A); \
        a0B = fmaf(vB.y, wa_##k1, a0B); a1B = fmaf(vB.y, wb_##k1, a1B); \
        a0A = fmaf(vA.z, wa_##k2, a0A); a1A = fmaf(vA.z, wb_##k2, a1A); \
        a0B = fmaf(vB.z, wa_##k2, a0B); a1B = fmaf(vB.z, wb_##k2, a1B); \
        a0A = fmaf(vA.w, wa_##k3, a0A); a1A = fmaf(vA.w, wb_##k3, a1A); \
        a0B = fmaf(vB.w, wa_##k3, a0B); a1B = fmaf(vB.w, wb_##k3, a1B); }
        KCH(0,   0,  1,  2,  3)
        KCH(1,   4,  5,  6,  7)
        KCH(2,   8,  9, 10, 11)
        KCH(3,  12, 13, 14, 15)
        KCH(4,  16, 17, 18, 19)
        KCH(5,  20, 21, 22, 23)
        KCH(6,  24, 25, 26, 27)
        KCH(7,  28, 29, 30, 31)
        KCH(8,  32, 33, 34, 35)
        KCH(9,  36, 37, 38, 39)
        KCH(10, 40, 41, 42, 43)
        KCH(11, 44, 45, 46, 47)
#undef KCH
        {
            const float2 vA = *(const float2*)(hpA + 48);
            const float2 vB = *(const float2*)(hpB + 48);
            a0A = fmaf(vA.x, wa_48, a0A); a1A = fmaf(vA.x, wb_48, a1A);
            a0B = fmaf(vB.x, wa_48, a0B); a1B = fmaf(vB.x, wb_48, a1B);
            a0A = fmaf(vA.y, wa_49, a0A); a1A = fmaf(vA.y, wb_49, a1A);
            a0B = fmaf(vB.y, wa_49, a0B); a1B = fmaf(vB.y, wb_49, a1B);
        }

        // Own-gate activations (wave-uniform role: w0=(i,f), w1=(g,o))
        float p0A, p1A, p0B, p1B;
        if (w == 0) {
            p0A = fast_sigmoid(a0A); p1A = fast_sigmoid(a1A);
            p0B = fast_sigmoid(a0B); p1B = fast_sigmoid(a1B);
        } else {
            p0A = fast_tanh(a0A);    p1A = fast_sigmoid(a1A);
            p0B = fast_tanh(a0B);    p1B = fast_sigmoid(a1B);
        }
        const int tb = t & 1;
        // idle lanes write identical values to slot 49 -> benign
        acts[tb][0][w][j] = make_float2(p0A, p1A);
        acts[tb][1][w][j] = make_float2(p0B, p1B);

        __syncthreads();   // the ONLY barrier per step

        const float2 qA = acts[tb][0][1 - w][j];
        const float2 qB = acts[tb][1][1 - w][j];
        const float iA = (w == 0) ? p0A : qA.x;
        const float fA = (w == 0) ? p1A : qA.y;
        const float gA = (w == 0) ? qA.x : p0A;
        const float oA = (w == 0) ? qA.y : p1A;
        const float iB = (w == 0) ? p0B : qB.x;
        const float fB = (w == 0) ? p1B : qB.y;
        const float gB = (w == 0) ? qB.x : p0B;
        const float oB = (w == 0) ? qB.y : p1B;

        cA = fmaf(fA, cA, iA * gA);
        cB = fmaf(fB, cB, iB * gB);
        hAr = oA * fast_tanh(cA);
        hBr = oB * fast_tanh(cB);
        // own-wave h copy for next step's broadcast (no cross-wave dep)
        hbuf[w][0][j] = hAr;
        hbuf[w][1][j] = hBr;
    }

    // Epilogue: wave w reduces chain w (w0 -> bA, w1 -> bA+1)
    const float hsel = (w == 0) ? hAr : hBr;
    const float hv   = (lane < HH) ? hsel : 0.0f;
    float r0 = hv * fc_w[0 * HH + j];
    float r1 = hv * fc_w[1 * HH + j];
    float r2 = hv * fc_w[2 * HH + j];
    #pragma unroll
    for (int off = 32; off > 0; off >>= 1) {
        r0 += __shfl_down(r0, off, 64);
        r1 += __shfl_down(r1, off, 64);
        r2 += __shfl_down(r2, off, 64);
    }
    if (lane == 0) {
        const int b = bA + w;
        out[b * 3 + 0] = r0 + fc_b[0];
        out[b * 3 + 1] = r1 + fc_b[1];
        out[b * 3 + 2] = r2 + fc_b[2];
    }
}

extern "C" void kernel_launch(void* const* d_in, const int* in_sizes, int n_in,
                              void* d_out, int out_size, void* d_ws, size_t ws_size,
                              hipStream_t stream) {
    const float* x    = (const float*)d_in[0];
    const float* W_ih = (const float*)d_in[1];
    const float* W_hh = (const float*)d_in[2];
    const float* b_ih = (const float*)d_in[3];
    const float* b_hh = (const float*)d_in[4];
    const float* fc_w = (const float*)d_in[5];
    const float* fc_b = (const float*)d_in[6];
    float* out = (float*)d_out;

    dim3 grid(BB / 2);    // 1024 blocks x 2 waves = 2048 waves = 2/SIMD
    dim3 block(128);
    lstm_pair_kernel<<<grid, block, 0, stream>>>(x, W_ih, W_hh, b_ih, b_hh,
                                                 fc_w, fc_b, out);
}

// Round 4
// 430.681 us; speedup vs baseline: 1.5336x; 1.2519x over previous
//
#include <hip/hip_runtime.h>

// LSTM: B=2048, T=512, D=1, H=50, OUT=3, fp32.
//
// R5: MFMA restructure. History:
//  R1 582 / R3 575 / R4 539 us: all VALU-issue-bound. Fitting one clock
//  across R1-R4 shows the chip runs ~1.3 GHz for this workload and
//  instruction counts match source (the "2.2x inflation" was a wrong
//  2.4 GHz assumption). VALU-FMA floor of the lane=unit mapping is
//  ~316 us -> must move the 50x200 recurrent matmul to the MFMA pipe.
//
// Design: block = 13 waves x 16 batches; wave w owns gate-row tile
// [16w, 16w+16) (13 tiles cover 200 rows + 8 pad). Per step:
//   Gates[208,16] = W[208,64] * H[64,16] via mfma_f32_16x16x32_bf16,
//   hi/lo bf16 split (3 terms) for fp32-class accuracy.
// A-frags (W hi/lo, 2 K-steps) live in 16 VGPRs, loaded once.
// B-frags are 4 raw ds_read_b128: h is stored in LDS PRE-CONVERTED as
// bf16-hi / bf16-lo u16 arrays by the update phase (conversion cost
// amortized once per h, not per consumer wave).
// Layout convention (cancels any hw k-permutation, m89-verified C/D):
//   A: row = lane&15, k = 8*(lane>>4)+e (+32/K-step); B: col = lane&15,
//   same k map; D: col(batch) = lane&15, row = 4*(lane>>4)+reg.
// Update: 800 (batch,unit) pairs, one per lane (tid<800), c in register.
// 2 barriers/step. Grid 128 x 832 threads.

#define BB 2048
#define TT 512
#define HH 50
#define NB 16            // batches per block
#define NW 13            // waves (gate tiles) per block
#define XP 513           // xs row stride (bank spread)
#define GP 209           // gact row stride (209%32=17 -> conflict-free update reads)
#define HS 80            // hfhi/hflo row stride in u16 (160B, 16B-aligned rows, 2-way banks)

typedef __attribute__((ext_vector_type(4))) float f32x4;
typedef __attribute__((ext_vector_type(8))) short s16x8;
typedef __attribute__((ext_vector_type(4))) int   i32x4;

__device__ __forceinline__ s16x8 pack_frag(int d0, int d1, int d2, int d3) {
    i32x4 v = {d0, d1, d2, d3};
    return __builtin_bit_cast(s16x8, v);
}

__global__ __launch_bounds__(NW * 64)
void lstm_mfma_kernel(const float* __restrict__ x,
                      const float* __restrict__ W_ih,
                      const float* __restrict__ W_hh,
                      const float* __restrict__ b_ih,
                      const float* __restrict__ b_hh,
                      const float* __restrict__ fc_w,
                      const float* __restrict__ fc_b,
                      float* __restrict__ out) {
    __shared__ float xs[NB * XP];                            // 32.8 KB
    __shared__ float gact[NB * GP];                          // 13.4 KB
    __shared__ __align__(16) unsigned short hfhi[NB * HS];   // 2.56 KB
    __shared__ __align__(16) unsigned short hflo[NB * HS];   // 2.56 KB

    const int tid  = threadIdx.x;
    const int w    = tid >> 6;          // wave id = gate tile id, 0..12
    const int lane = tid & 63;
    const int b0   = blockIdx.x * NB;

    // ---- stage x rows (coalesced) and zero the h hi/lo state ----
    for (int idx = tid; idx < NB * TT; idx += NW * 64) {
        xs[(idx >> 9) * XP + (idx & 511)] = x[(b0 + (idx >> 9)) * TT + (idx & 511)];
    }
    for (int idx = tid; idx < NB * HS; idx += NW * 64) {
        hfhi[idx] = 0; hflo[idx] = 0;
    }

    // ---- A-fragments: W_hh rows for this wave's tile, bf16 hi/lo ----
    // lane supplies A row arow = 16w + (lane&15); elems e: k = 32s + 8g + e
    const int g    = lane >> 4;
    const int arow = 16 * w + (lane & 15);
    int ahi[2][4], alo[2][4];
    #pragma unroll
    for (int s = 0; s < 2; ++s) {
        #pragma unroll
        for (int d = 0; d < 4; ++d) {
            const int k0 = 32 * s + 8 * g + 2 * d;
            const int k1 = k0 + 1;
            const float w0 = (arow < 4 * HH && k0 < HH) ? W_hh[arow * HH + k0] : 0.0f;
            const float w1 = (arow < 4 * HH && k1 < HH) ? W_hh[arow * HH + k1] : 0.0f;
            const unsigned u0 = __float_as_uint(w0);
            const unsigned u1 = __float_as_uint(w1);
            ahi[s][d] = (int)((u1 & 0xffff0000u) | (u0 >> 16));
            const float r0 = w0 - __uint_as_float(u0 & 0xffff0000u);
            const float r1 = w1 - __uint_as_float(u1 & 0xffff0000u);
            alo[s][d] = (int)((__float_as_uint(r1) & 0xffff0000u) |
                              (__float_as_uint(r0) >> 16));
        }
    }
    const s16x8 Ah0 = pack_frag(ahi[0][0], ahi[0][1], ahi[0][2], ahi[0][3]);
    const s16x8 Ah1 = pack_frag(ahi[1][0], ahi[1][1], ahi[1][2], ahi[1][3]);
    const s16x8 Al0 = pack_frag(alo[0][0], alo[0][1], alo[0][2], alo[0][3]);
    const s16x8 Al1 = pack_frag(alo[1][0], alo[1][1], alo[1][2], alo[1][3]);

    // ---- per-reg output-row params: D row = 16w + 4g + r ----
    float wih_[4], bs_[4], aP_[4], bP_[4], c0_[4];
    #pragma unroll
    for (int r = 0; r < 4; ++r) {
        const int row = 16 * w + 4 * g + r;
        const bool real = (row < 4 * HH);
        wih_[r] = real ? W_ih[row] : 0.0f;
        bs_[r]  = real ? (b_ih[row] + b_hh[row]) : 0.0f;
        const bool isG = (row >= 2 * HH) && (row < 3 * HH);   // tanh gate
        aP_[r] = isG ? 2.0f : 1.0f;
        bP_[r] = 1.0f - aP_[r];
        c0_[r] = -1.4426950408889634f * aP_[r];
    }

    // ---- update-lane mapping: pair p = tid -> (batch, unit) ----
    const int  ub  = tid & 15;
    const int  uu  = tid >> 4;
    const bool upd = (tid < NB * HH);   // 800 lanes
    float c = 0.0f, hreg = 0.0f;

    // ---- B-frag LDS pointers (col = lane&15, k = 8g+e (+32)) ----
    const int bcol = lane & 15;
    const s16x8* bh0 = (const s16x8*)(hfhi + bcol * HS + 8 * g);
    const s16x8* bh1 = (const s16x8*)(hfhi + bcol * HS + 32 + 8 * g);
    const s16x8* bl0 = (const s16x8*)(hflo + bcol * HS + 8 * g);
    const s16x8* bl1 = (const s16x8*)(hflo + bcol * HS + 32 + 8 * g);

    __syncthreads();

    #pragma unroll 1
    for (int t = 0; t < TT; ++t) {
        // P1: load B-frags (h state from step t-1, pre-converted)
        const s16x8 Bh0 = *bh0, Bh1 = *bh1, Bl0 = *bl0, Bl1 = *bl1;

        // P2: bias + x-projection into C, then 6 MFMAs (2 acc chains)
        const float xv = xs[bcol * XP + t];
        f32x4 acc, acc2;
        #pragma unroll
        for (int r = 0; r < 4; ++r) {
            acc[r]  = fmaf(xv, wih_[r], bs_[r]);
            acc2[r] = 0.0f;
        }
        acc  = __builtin_amdgcn_mfma_f32_16x16x32_bf16(Ah0, Bh0, acc,  0, 0, 0);
        acc  = __builtin_amdgcn_mfma_f32_16x16x32_bf16(Ah1, Bh1, acc,  0, 0, 0);
        acc2 = __builtin_amdgcn_mfma_f32_16x16x32_bf16(Ah0, Bl0, acc2, 0, 0, 0);
        acc2 = __builtin_amdgcn_mfma_f32_16x16x32_bf16(Ah1, Bl1, acc2, 0, 0, 0);
        acc2 = __builtin_amdgcn_mfma_f32_16x16x32_bf16(Al0, Bh0, acc2, 0, 0, 0);
        acc2 = __builtin_amdgcn_mfma_f32_16x16x32_bf16(Al1, Bh1, acc2, 0, 0, 0);

        // P3+P4: activations (branchless sigmoid/tanh) -> gact
        #pragma unroll
        for (int r = 0; r < 4; ++r) {
            const float v = acc[r] + acc2[r];
            const float e = __builtin_amdgcn_exp2f(c0_[r] * v);
            const float a = fmaf(aP_[r], __builtin_amdgcn_rcpf(1.0f + e), bP_[r]);
            gact[bcol * GP + (16 * w + 4 * g + r)] = a;
        }

        __syncthreads();

        // P5: elementwise c/h update, one (batch,unit) pair per lane;
        //     writes h back PRE-CONVERTED to bf16 hi/lo.
        if (upd) {
            const float iv = gact[ub * GP + uu];
            const float fv = gact[ub * GP + HH + uu];
            const float gv = gact[ub * GP + 2 * HH + uu];
            const float ov = gact[ub * GP + 3 * HH + uu];
            c = fmaf(fv, c, iv * gv);
            const float e2 = __builtin_amdgcn_exp2f(-2.8853900817779268f * c);
            const float th = fmaf(2.0f, __builtin_amdgcn_rcpf(1.0f + e2), -1.0f);
            hreg = ov * th;
            const unsigned hu = __float_as_uint(hreg);
            hfhi[ub * HS + uu] = (unsigned short)(hu >> 16);
            const float res = hreg - __uint_as_float(hu & 0xffff0000u);
            hflo[ub * HS + uu] = (unsigned short)(__float_as_uint(res) >> 16);
        }

        __syncthreads();
    }

    // ---- epilogue: out[b][o] = h . fc_w[o] + fc_b[o] ----
    if (upd) gact[uu * NB + ub] = hreg;   // h[unit][batch]
    __syncthreads();
    if (tid < NB * 3) {
        const int b = tid / 3, o = tid % 3;
        float s = fc_b[o];
        for (int u = 0; u < HH; ++u)
            s = fmaf(gact[u * NB + b], fc_w[o * HH + u], s);
        out[(b0 + b) * 3 + o] = s;
    }
}

extern "C" void kernel_launch(void* const* d_in, const int* in_sizes, int n_in,
                              void* d_out, int out_size, void* d_ws, size_t ws_size,
                              hipStream_t stream) {
    const float* x    = (const float*)d_in[0];
    const float* W_ih = (const float*)d_in[1];
    const float* W_hh = (const float*)d_in[2];
    const float* b_ih = (const float*)d_in[3];
    const float* b_hh = (const float*)d_in[4];
    const float* fc_w = (const float*)d_in[5];
    const float* fc_b = (const float*)d_in[6];
    float* out = (float*)d_out;

    dim3 grid(BB / NB);      // 128 blocks
    dim3 block(NW * 64);     // 832 threads = 13 waves
    lstm_mfma_kernel<<<grid, block, 0, stream>>>(x, W_ih, W_hh, b_ih, b_hh,
                                                 fc_w, fc_b, out);
}

// Round 5
// 336.333 us; speedup vs baseline: 1.9638x; 1.2805x over previous
//
#include <hip/hip_runtime.h>

// LSTM: B=2048, T=512, D=1, H=50, OUT=3, fp32.
//
// R6: fused-update MFMA. History:
//  R1-R4 (582..539us): VALU-issue-bound lane=unit designs; floor ~316us.
//  R5 (430us, dispatch 381): MFMA gates + LDS exchange. MfmaUtil 8.8,
//     VALU 19.6 -> latency/barrier-bound: 2 barriers + 2 LDS round-trips
//     per step, 2.3e7 bank-conflict cycles (HS=80 uneven b128 slots).
//
// R6 changes:
//  * A-row permutation: tile w rows ordered (gate=tr&3, unit=4w+tr>>2).
//    D mapping (row=4*hi+reg) then gives each lane ALL FOUR gate preacts
//    of its (unit=4w+hi, batch=lane&15) pair in acc[0..3] -> update is
//    lane-local register math. gact array, update phase and the second
//    barrier are GONE. c lives in a register.
//  * h state: double-buffered hf[buf][hi/lo][batch=16][HS=72] u16.
//    Row stride 144B -> ds_read_b128 16B-slot distribution is perfectly
//    even (8 lanes per slot position = inherent minimum, no excess
//    conflicts). Write h pre-split into bf16 hi/lo.
//  * ONE __syncthreads per step (write nxt buf, barrier, read it).
// Layout conventions identical to R5 (verified by its pass):
//  A: row=lane&15, k=8*(lane>>4)+e (+32/K-step); B: col=lane&15, same k;
//  D: col=lane&15, row=4*(lane>>4)+reg. hi/lo bf16 3-term split.
// Block: 13 waves x 64; grid 128 (per-SIMD work is invariant in NB; 16
// batch cols fully used).

#define BB 2048
#define TT 512
#define HH 50
#define NB 16            // batches per block (= MFMA cols, all real)
#define NW 13            // waves: 13 tiles x 4 units = 52 >= 50 units
#define XP 513           // xs row stride (floats)
#define HS 72            // hf slot stride per batch row (u16; 144B rows)

typedef __attribute__((ext_vector_type(4))) float f32x4;
typedef __attribute__((ext_vector_type(8))) short s16x8;
typedef __attribute__((ext_vector_type(4))) int   i32x4;

__device__ __forceinline__ s16x8 pack_frag(int d0, int d1, int d2, int d3) {
    i32x4 v = {d0, d1, d2, d3};
    return __builtin_bit_cast(s16x8, v);
}

__device__ __forceinline__ float fast_sigmoid(float x) {
    float e = __builtin_amdgcn_exp2f(-1.4426950408889634f * x);
    return __builtin_amdgcn_rcpf(1.0f + e);
}

__device__ __forceinline__ float fast_tanh(float x) {
    float e = __builtin_amdgcn_exp2f(-2.8853900817779268f * x);  // e^{-2x}
    return __builtin_amdgcn_rcpf(1.0f + e) * 2.0f - 1.0f;
}

__global__ __launch_bounds__(NW * 64)
void lstm_fused_kernel(const float* __restrict__ x,
                       const float* __restrict__ W_ih,
                       const float* __restrict__ W_hh,
                       const float* __restrict__ b_ih,
                       const float* __restrict__ b_hh,
                       const float* __restrict__ fc_w,
                       const float* __restrict__ fc_b,
                       float* __restrict__ out) {
    __shared__ float xs[NB * XP];                              // 32.8 KB
    __shared__ __align__(16) unsigned short hf[2][2][NB][HS];  // 9.2 KB
    __shared__ float hfin[NB][64];                             // 4 KB

    const int tid  = threadIdx.x;
    const int w    = tid >> 6;          // wave id = tile id, 0..12
    const int lane = tid & 63;
    const int hi   = lane >> 4;
    const int bcol = lane & 15;         // batch column
    const int b0   = blockIdx.x * NB;

    // ---- stage x rows (coalesced) ----
    for (int idx = tid; idx < NB * TT; idx += NW * 64) {
        xs[(idx >> 9) * XP + (idx & 511)] = x[(b0 + (idx >> 9)) * TT + (idx & 511)];
    }
    // ---- zero h state (both buffers, incl. pad slots 52..71) ----
    for (int idx = tid; idx < (int)(sizeof(hf) / 4); idx += NW * 64) {
        ((unsigned*)hf)[idx] = 0;
    }

    // ---- A-fragments: permuted rows (gate=tr&3, unit=4w+tr>>2), hi/lo ----
    const int tr = bcol;                    // tile-row this lane supplies
    const int ga = tr & 3;                  // gate of this tile-row
    const int ua = 4 * w + (tr >> 2);       // unit of this tile-row
    const bool arow_ok = (ua < HH);
    int ahi[2][4], alo[2][4];
    #pragma unroll
    for (int s = 0; s < 2; ++s) {
        #pragma unroll
        for (int d = 0; d < 4; ++d) {
            const int k0 = 32 * s + 8 * hi + 2 * d;
            const int k1 = k0 + 1;
            const float w0 = (arow_ok && k0 < HH) ? W_hh[(ga * HH + ua) * HH + k0] : 0.0f;
            const float w1 = (arow_ok && k1 < HH) ? W_hh[(ga * HH + ua) * HH + k1] : 0.0f;
            const unsigned u0 = __float_as_uint(w0);
            const unsigned u1 = __float_as_uint(w1);
            ahi[s][d] = (int)((u1 & 0xffff0000u) | (u0 >> 16));
            const float r0 = w0 - __uint_as_float(u0 & 0xffff0000u);
            const float r1 = w1 - __uint_as_float(u1 & 0xffff0000u);
            alo[s][d] = (int)((__float_as_uint(r1) & 0xffff0000u) |
                              (__float_as_uint(r0) >> 16));
        }
    }
    const s16x8 Ah0 = pack_frag(ahi[0][0], ahi[0][1], ahi[0][2], ahi[0][3]);
    const s16x8 Ah1 = pack_frag(ahi[1][0], ahi[1][1], ahi[1][2], ahi[1][3]);
    const s16x8 Al0 = pack_frag(alo[0][0], alo[0][1], alo[0][2], alo[0][3]);
    const s16x8 Al1 = pack_frag(alo[1][0], alo[1][1], alo[1][2], alo[1][3]);

    // ---- this lane's (unit, batch) pair and per-gate params ----
    const int  u    = 4 * w + hi;           // unit owned by this lane
    const bool u_ok = (u < HH);
    float wih_[4], bs_[4];
    #pragma unroll
    for (int r = 0; r < 4; ++r) {           // gate r rows: r*HH + u
        wih_[r] = u_ok ? W_ih[r * HH + u] : 0.0f;
        bs_[r]  = u_ok ? (b_ih[r * HH + u] + b_hh[r * HH + u]) : 0.0f;
    }

    // ---- LDS bases (u16 units). part stride 1152, buf stride 2304 ----
    const unsigned short* rb = &hf[0][0][bcol][8 * hi];   // B-frag reads
    unsigned short*       wbp = &hf[0][0][bcol][u];       // h writes

    float c = 0.0f, hcur = 0.0f;

    __syncthreads();

    // One step: read buf CB, write buf 1-CB, one barrier.
#define STEP(CB, T) { \
        const s16x8 Bh0 = *(const s16x8*)(rb + (CB) * 2304); \
        const s16x8 Bh1 = *(const s16x8*)(rb + (CB) * 2304 + 32); \
        const s16x8 Bl0 = *(const s16x8*)(rb + (CB) * 2304 + 1152); \
        const s16x8 Bl1 = *(const s16x8*)(rb + (CB) * 2304 + 1152 + 32); \
        const float xv = xs[bcol * XP + (T)]; \
        f32x4 acc, acc2; \
        _Pragma("unroll") \
        for (int r = 0; r < 4; ++r) { acc[r] = fmaf(xv, wih_[r], bs_[r]); acc2[r] = 0.0f; } \
        acc  = __builtin_amdgcn_mfma_f32_16x16x32_bf16(Ah0, Bh0, acc,  0, 0, 0); \
        acc  = __builtin_amdgcn_mfma_f32_16x16x32_bf16(Ah1, Bh1, acc,  0, 0, 0); \
        acc2 = __builtin_amdgcn_mfma_f32_16x16x32_bf16(Ah0, Bl0, acc2, 0, 0, 0); \
        acc2 = __builtin_amdgcn_mfma_f32_16x16x32_bf16(Ah1, Bl1, acc2, 0, 0, 0); \
        acc2 = __builtin_amdgcn_mfma_f32_16x16x32_bf16(Al0, Bh0, acc2, 0, 0, 0); \
        acc2 = __builtin_amdgcn_mfma_f32_16x16x32_bf16(Al1, Bh1, acc2, 0, 0, 0); \
        const float iv = fast_sigmoid(acc[0] + acc2[0]); \
        const float fv = fast_sigmoid(acc[1] + acc2[1]); \
        const float gv = fast_tanh   (acc[2] + acc2[2]); \
        const float ov = fast_sigmoid(acc[3] + acc2[3]); \
        c    = fmaf(fv, c, iv * gv); \
        hcur = ov * fast_tanh(c); \
        const unsigned hu = __float_as_uint(hcur); \
        wbp[(1 - (CB)) * 2304] = (unsigned short)(hu >> 16); \
        const float res = hcur - __uint_as_float(hu & 0xffff0000u); \
        wbp[(1 - (CB)) * 2304 + 1152] = (unsigned short)(__float_as_uint(res) >> 16); \
        __syncthreads(); }

    #pragma unroll 1
    for (int t = 0; t < TT; t += 2) {
        STEP(0, t)
        STEP(1, t + 1)
    }
#undef STEP

    // ---- epilogue: h_T dot fc_w (once) ----
    hfin[bcol][u] = hcur;           // u <= 51 < 64; pad units ignored below
    __syncthreads();
    if (tid < NB * 3) {
        const int b = tid / 3, o = tid % 3;
        float s = fc_b[o];
        for (int uu = 0; uu < HH; ++uu)
            s = fmaf(hfin[b][uu], fc_w[o * HH + uu], s);
        out[(b0 + b) * 3 + o] = s;
    }
}

extern "C" void kernel_launch(void* const* d_in, const int* in_sizes, int n_in,
                              void* d_out, int out_size, void* d_ws, size_t ws_size,
                              hipStream_t stream) {
    const float* x    = (const float*)d_in[0];
    const float* W_ih = (const float*)d_in[1];
    const float* W_hh = (const float*)d_in[2];
    const float* b_ih = (const float*)d_in[3];
    const float* b_hh = (const float*)d_in[4];
    const float* fc_w = (const float*)d_in[5];
    const float* fc_b = (const float*)d_in[6];
    float* out = (float*)d_out;

    dim3 grid(BB / NB);      // 128 blocks
    dim3 block(NW * 64);     // 832 threads = 13 waves
    lstm_fused_kernel<<<grid, block, 0, stream>>>(x, W_ih, W_hh, b_ih, b_hh,
                                                  fc_w, fc_b, out);
}